// Round 7
// baseline (25.974 us; speedup 1.0000x reference)
//
#include <hip/hip_runtime.h>
#include <math.h>

#define Sd 52
#define SS (Sd*Sd)      // 2704
#define Cc 80
#define NCc 85
#define NCH 255
#define Bb 64
#define Mm 50
#define DIVc 8.0f
#define KB 8                    // blocks per batch
#define NBLK (Bb*KB)            // 512
#define BCE_SH  ((Mm*Cc)/KB)    // 500
#define NO_TOT  (3*SS)          // 8112
#define NO_SH   (NO_TOT/KB)     // 1014

__device__ __constant__ float AW[9] = {10.f,16.f,33.f,30.f,62.f,59.f,116.f,156.f,373.f};
__device__ __constant__ float AH[9] = {13.f,30.f,23.f,61.f,45.f,119.f,90.f,198.f,326.f};

struct Dec {
    int   idx, valid, now, cell, off;
    float ax, ay, w, h;
};

// Reference's quirky anchor IoU + cell decode; pure function of geo[b,m].
// Argmax via cross-multiplication (CM,D all > 0 for this data): no divides.
__device__ __forceinline__ Dec decode(const float4* __restrict__ geo4, int b, int m) {
    Dec d;
    const float4 g = geo4[b*Mm + m];
    const float cx = g.x, cy = g.y, w = g.z, h = g.w;
    // A=(aw+1)(ah+1), Bv=(w+1)(h+1), CM=(min(aw,w)+1)*(min(ah,h)-1), D=A+Bv-CM
    const float Bv = (w+1.f)*(h+1.f);
    float bCM = (fminf(AW[0],w)+1.f)*(fminf(AH[0],h)-1.f);
    float bD  = (AW[0]+1.f)*(AH[0]+1.f) + Bv - bCM;
    int idx = 0;
    #pragma unroll
    for (int i = 1; i < 9; ++i) {
        const float CM = (fminf(AW[i],w)+1.f)*(fminf(AH[i],h)-1.f);
        const float D  = (AW[i]+1.f)*(AH[i]+1.f) + Bv - CM;
        if (CM*bD > bCM*D) { bCM = CM; bD = D; idx = i; }  // first-max tie-break
    }
    d.idx   = idx;
    d.valid = (idx <= 2) ? 1 : 0;
    d.now   = idx < 2 ? idx : 2;
    int ix = (int)(cx * 0.125f); ix = ix < 0 ? 0 : (ix > Sd-1 ? Sd-1 : ix);
    int iy = (int)(cy * 0.125f); iy = iy < 0 ? 0 : (iy > Sd-1 ? Sd-1 : iy);
    d.cell = ix*Sd + iy;
    d.off  = (b*NCH + d.now*NCc)*SS + d.cell;
    d.ax = (cx - (float)ix*DIVc) * 0.125f;
    d.ay = (cy - (float)iy*DIVc) * 0.125f;
    d.w = w; d.h = h;
    return d;
}

__global__ __launch_bounds__(256, 2) void yolo_fused(
    const float*  __restrict__ x,      // (B, 255, 52, 52)
    const float4* __restrict__ geo4,   // (B, 50) float4
    const int*    __restrict__ cls,    // (B, 50)
    float* __restrict__ out,           // (1,)
    float* __restrict__ partial,       // (NBLK,) in d_ws
    unsigned int* __restrict__ ctrs)   // hierarchical counters, 128B-strided
{
    const int blk = blockIdx.x;
    const int b   = blk >> 3;
    const int k   = blk & (KB-1);
    const int tid = threadIdx.x;

    __shared__ uint4 rem4[NO_TOT/16];            // 8112 B bitmap (now, s1, s2)
    unsigned char* removed = (unsigned char*)rem4;
    __shared__ float wsf[4], wsn[4];
    __shared__ int   wsc[4];
    __shared__ int   fin;

    // ===== issue ALL scattered global loads up front (latency overlap) =====
    // BCE pair 0: every thread re-decodes its own box (no barrier dependency).
    const int t0 = k*BCE_SH + tid;
    const int m0 = t0 / Cc, c0 = t0 - m0*Cc;
    const Dec d0 = decode(geo4, b, m0);
    const int cls0 = cls[b*Mm + m0];
    const float v0 = x[d0.off + (5+c0)*SS];          // in-bounds even if !valid

    // BCE pair 1 (tid < 244); clamp index for inactive lanes, mask at use.
    const bool has1 = tid < (BCE_SH - 256);
    const int t1 = t0 + 256;
    const int m1 = has1 ? t1 / Cc : m0;
    const int c1 = has1 ? (t1 - m1*Cc) : c0;
    const Dec d1 = decode(geo4, b, m1);
    const int cls1 = cls[b*Mm + m1];
    const float v1 = x[d1.off + (5+c1)*SS];

    // noobj preloads (coalesced, 4 per thread; only i=3 can be out-of-share)
    const float* xb = x + (size_t)b*NCH*SS;
    float pre[4]; int tix[4]; bool pm[4];
    #pragma unroll
    for (int i = 0; i < 4; ++i) {
        const int t = k*NO_SH + tid + i*256;
        pm[i]  = (t < (k+1)*NO_SH);
        tix[i] = pm[i] ? t : k*NO_SH;
        const int nw = tix[i] / SS, s = tix[i] - nw*SS;
        pre[i] = xb[nw*NCc*SS + s];
    }

    // phase-1 decode (tid<50) + coord-channel loads (k==0 blocks only)
    Dec dp; dp.valid = 0; dp.now = 0; dp.cell = 0; dp.idx = 0;
    float e0=0.f, e1=0.f, e2=0.f, e3=0.f, e4=0.f;
    const bool p1 = (tid < Mm);
    if (p1) {
        dp = decode(geo4, b, tid);
        if (k == 0) {
            e0 = x[dp.off];
            e1 = x[dp.off + 1*SS];
            e2 = x[dp.off + 2*SS];
            e3 = x[dp.off + 3*SS];
            e4 = x[dp.off + 4*SS];
        }
    }

    // ===== zero bitmap while loads are in flight (uint4: 2 iters) =====
    const uint4 z4 = {0u,0u,0u,0u};
    #pragma unroll
    for (int i = tid; i < NO_TOT/16; i += 256) rem4[i] = z4;
    __syncthreads();

    float lsum = 0.f;

    // ===== Phase 1: mark bitmap; coord loss once per batch (k==0) =====
    if (p1 && dp.valid) {
        removed[dp.now*SS + dp.cell] = 1;
        if (k == 0) {
            const float rax = 1.f/(1.f+expf(-e1));
            const float ray = 1.f/(1.f+expf(-e2));
            const float rw  = AW[dp.idx]*expf(e3);
            const float rh  = AH[dp.idx]*expf(e4);

            // iou_t with the reference's quirky formula (y1+1 inside the max)
            const float X1 = rax*DIVc - rw*0.5f, Y1 = ray*DIVc - rh*0.5f;
            const float X2 = rax*DIVc + rw*0.5f, Y2 = ray*DIVc + rh*0.5f;
            const float x1 = dp.ax*DIVc - dp.w*0.5f, y1 = dp.ay*DIVc - dp.h*0.5f;
            const float x2 = dp.ax*DIVc + dp.w*0.5f, y2 = dp.ay*DIVc + dp.h*0.5f;
            const float Bv  = (dp.w+1.f)*(dp.h+1.f);
            const float A2  = (rw+1.f)*(rh+1.f);
            const float CM2 = (fminf(X2,x2)-fmaxf(X1,x1)+1.f) *
                              (fminf(Y2,y2)-fmaxf(Y1,y1+1.f));
            const float iou_t = CM2/(A2+Bv-CM2);

            const float q0 = e0-iou_t, q1 = rax-dp.ax, q2 = ray-dp.ay,
                        q3 = rw-dp.w,  q4 = rh-dp.h;
            lsum += 5.f*q0*q0 + q1*q1 + q2*q2 + q3*q3 + q4*q4;
        }
    }

    // ===== Phase 2: BCE from prefetched v0/v1 (independent of bitmap) =====
    if (d0.valid) {
        const float label = 1.f/(1.f+expf(-v0));
        const float term = (cls0 == c0) ? fmaxf(logf(label),    -100.f)
                                        : fmaxf(log1pf(-label), -100.f);
        lsum -= term * (1.f/(float)Cc);
    }
    if (has1 && d1.valid) {
        const float label = 1.f/(1.f+expf(-v1));
        const float term = (cls1 == c1) ? fmaxf(logf(label),    -100.f)
                                        : fmaxf(log1pf(-label), -100.f);
        lsum -= term * (1.f/(float)Cc);
    }

    __syncthreads();   // bitmap complete

    // ===== Phase 3: noobj num (prefetched) + full-bitmap count =====
    float num = 0.f;
    #pragma unroll
    for (int i = 0; i < 4; ++i)
        if (pm[i] && !removed[tix[i]]) num += pre[i]*pre[i];

    int cnt = 0;
    #pragma unroll
    for (int i = tid; i < NO_TOT/16; i += 256) {
        const uint4 wd = rem4[i];
        const unsigned s = ((wd.x * 0x01010101u) >> 24)
                         + ((wd.y * 0x01010101u) >> 24)
                         + ((wd.z * 0x01010101u) >> 24)
                         + ((wd.w * 0x01010101u) >> 24);
        cnt += (int)s;
    }

    // ===== block reduce via shuffles =====
    #pragma unroll
    for (int o = 32; o > 0; o >>= 1) {
        lsum += __shfl_down(lsum, o);
        num  += __shfl_down(num,  o);
        cnt  += __shfl_down(cnt,  o);
    }
    const int wv = tid >> 6;
    if ((tid & 63) == 0) { wsf[wv] = lsum; wsn[wv] = num; wsc[wv] = cnt; }
    __syncthreads();

    // ===== hierarchical last-block tail (single dispatch, low contention) ===
    // atomicInc(ptr,7) wrap protocol: exactly 8 incs/counter/replay; detector
    // old==6 is the 8th arrival for any start state >= 7 (0xAA poison) or the
    // steady-state leave-behind (7). Self-reinitializing (r4-validated).
    if (tid == 0) {
        const float F  = wsf[0]+wsf[1]+wsf[2]+wsf[3];
        const float Nn = wsn[0]+wsn[1]+wsn[2]+wsn[3];
        const int   Ct = wsc[0]+wsc[1]+wsc[2]+wsc[3];
        const float pval = F + 0.5f * Nn / (float)(NO_TOT - Ct);
        __hip_atomic_store(&partial[blk], pval, __ATOMIC_RELEASE,
                           __HIP_MEMORY_SCOPE_AGENT);
        __threadfence();
        int f = 0;
        // level 1: 64 counters; members blk, blk+64, ... (same XCD: blk mod 8)
        const int g1 = blk & 63;
        if (atomicInc(&ctrs[g1*32], 7u) == 6u) {
            __threadfence();
            // level 2: 8 counters; members are level-1 winners, XCD-local
            const int g2 = g1 & 7;
            if (atomicInc(&ctrs[(64 + g2)*32], 7u) == 6u) {
                __threadfence();
                // level 3: single counter, only 8 cross-XCD RMWs
                if (atomicInc(&ctrs[72*32], 7u) == 6u) f = 1;
            }
        }
        fin = f;
    }
    __syncthreads();

    // ===== finisher: deterministic fixed-order reduce of 512 partials =====
    if (fin) {
        __threadfence();
        float v = __hip_atomic_load(&partial[tid],       __ATOMIC_RELAXED,
                                    __HIP_MEMORY_SCOPE_AGENT)
                + __hip_atomic_load(&partial[tid + 256], __ATOMIC_RELAXED,
                                    __HIP_MEMORY_SCOPE_AGENT);
        #pragma unroll
        for (int o = 32; o > 0; o >>= 1) v += __shfl_down(v, o);
        if ((tid & 63) == 0) wsf[tid >> 6] = v;
        __syncthreads();
        if (tid == 0) out[0] = wsf[0] + wsf[1] + wsf[2] + wsf[3];
    }
}

extern "C" void kernel_launch(void* const* d_in, const int* in_sizes, int n_in,
                              void* d_out, int out_size, void* d_ws, size_t ws_size,
                              hipStream_t stream) {
    const float*  x    = (const float*)d_in[0];
    const float4* geo4 = (const float4*)d_in[1];
    const int*    cls  = (const int*)d_in[2];
    float* out     = (float*)d_out;
    float* partial = (float*)d_ws;                          // 512 floats
    unsigned int* ctrs = (unsigned int*)(partial + NBLK);   // 73 x 128B-strided

    yolo_fused<<<NBLK, 256, 0, stream>>>(x, geo4, cls, out, partial, ctrs);
}

// Round 8
// 16.187 us; speedup vs baseline: 1.6046x; 1.6046x over previous
//
#include <hip/hip_runtime.h>
#include <math.h>

#define Sd 52
#define SS (Sd*Sd)      // 2704
#define Cc 80
#define NCc 85
#define NCH 255
#define Bb 64
#define Mm 50
#define DIVc 8.0f
#define KB 8                    // blocks per batch
#define NBLK (Bb*KB)            // 512
#define BCE_SH  ((Mm*Cc)/KB)    // 500
#define NO_TOT  (3*SS)          // 8112
#define NO_SH   (NO_TOT/KB)     // 1014

__device__ __constant__ float AW[9] = {10.f,16.f,33.f,30.f,62.f,59.f,116.f,156.f,373.f};
__device__ __constant__ float AH[9] = {13.f,30.f,23.f,61.f,45.f,119.f,90.f,198.f,326.f};

struct Dec {
    int   idx, valid, now, cell, off;
    float ax, ay, w, h;
};

// Reference's quirky anchor IoU + cell decode; pure function of geo[b,m].
// Argmax via cross-multiplication (CM,D all > 0 for this data): no divides.
__device__ __forceinline__ Dec decode(const float4* __restrict__ geo4, int b, int m) {
    Dec d;
    const float4 g = geo4[b*Mm + m];
    const float cx = g.x, cy = g.y, w = g.z, h = g.w;
    // A=(aw+1)(ah+1), Bv=(w+1)(h+1), CM=(min(aw,w)+1)*(min(ah,h)-1), D=A+Bv-CM
    const float Bv = (w+1.f)*(h+1.f);
    float bCM = (fminf(AW[0],w)+1.f)*(fminf(AH[0],h)-1.f);
    float bD  = (AW[0]+1.f)*(AH[0]+1.f) + Bv - bCM;
    int idx = 0;
    #pragma unroll
    for (int i = 1; i < 9; ++i) {
        const float CM = (fminf(AW[i],w)+1.f)*(fminf(AH[i],h)-1.f);
        const float D  = (AW[i]+1.f)*(AH[i]+1.f) + Bv - CM;
        if (CM*bD > bCM*D) { bCM = CM; bD = D; idx = i; }  // first-max tie-break
    }
    d.idx   = idx;
    d.valid = (idx <= 2) ? 1 : 0;
    d.now   = idx < 2 ? idx : 2;
    int ix = (int)(cx * 0.125f); ix = ix < 0 ? 0 : (ix > Sd-1 ? Sd-1 : ix);
    int iy = (int)(cy * 0.125f); iy = iy < 0 ? 0 : (iy > Sd-1 ? Sd-1 : iy);
    d.cell = ix*Sd + iy;
    d.off  = (b*NCH + d.now*NCc)*SS + d.cell;
    d.ax = (cx - (float)ix*DIVc) * 0.125f;
    d.ay = (cy - (float)iy*DIVc) * 0.125f;
    d.w = w; d.h = h;
    return d;
}

__global__ __launch_bounds__(256, 2) void yolo_fused(
    const float*  __restrict__ x,      // (B, 255, 52, 52)
    const float4* __restrict__ geo4,   // (B, 50) float4
    const int*    __restrict__ cls,    // (B, 50)
    float* __restrict__ out,           // (1,)
    float* __restrict__ partial,       // (NBLK,) in d_ws
    unsigned int* __restrict__ ctr)    // 1 uint in d_ws
{
    const int blk = blockIdx.x;
    const int b   = blk >> 3;
    const int k   = blk & (KB-1);
    const int tid = threadIdx.x;

    __shared__ uint4 rem4[NO_TOT/16];            // 8112 B bitmap (now, s1, s2)
    unsigned char* removed = (unsigned char*)rem4;
    __shared__ float wsf[4], wsn[4];
    __shared__ int   wsc[4];
    __shared__ int   fin;

    // ===== issue ALL scattered global loads up front (latency overlap) =====
    // BCE pair 0: every thread re-decodes its own box (no barrier dependency).
    const int t0 = k*BCE_SH + tid;
    const int m0 = t0 / Cc, c0 = t0 - m0*Cc;
    const Dec d0 = decode(geo4, b, m0);
    const int cls0 = cls[b*Mm + m0];
    const float v0 = x[d0.off + (5+c0)*SS];          // in-bounds even if !valid

    // BCE pair 1 (tid < 244); clamp index for inactive lanes, mask at use.
    const bool has1 = tid < (BCE_SH - 256);
    const int t1 = t0 + 256;
    const int m1 = has1 ? t1 / Cc : m0;
    const int c1 = has1 ? (t1 - m1*Cc) : c0;
    const Dec d1 = decode(geo4, b, m1);
    const int cls1 = cls[b*Mm + m1];
    const float v1 = x[d1.off + (5+c1)*SS];

    // noobj preloads (coalesced, 4 per thread; only i=3 can be out-of-share)
    const float* xb = x + (size_t)b*NCH*SS;
    float pre[4]; int tix[4]; bool pm[4];
    #pragma unroll
    for (int i = 0; i < 4; ++i) {
        const int t = k*NO_SH + tid + i*256;
        pm[i]  = (t < (k+1)*NO_SH);
        tix[i] = pm[i] ? t : k*NO_SH;
        const int nw = tix[i] / SS, s = tix[i] - nw*SS;
        pre[i] = xb[nw*NCc*SS + s];
    }

    // phase-1 decode (tid<50) + coord-channel loads (k==0 blocks only)
    Dec dp; dp.valid = 0; dp.now = 0; dp.cell = 0; dp.idx = 0;
    float e0=0.f, e1=0.f, e2=0.f, e3=0.f, e4=0.f;
    const bool p1 = (tid < Mm);
    if (p1) {
        dp = decode(geo4, b, tid);
        if (k == 0) {
            e0 = x[dp.off];
            e1 = x[dp.off + 1*SS];
            e2 = x[dp.off + 2*SS];
            e3 = x[dp.off + 3*SS];
            e4 = x[dp.off + 4*SS];
        }
    }

    // ===== zero bitmap while loads are in flight (uint4: 2 iters) =====
    const uint4 z4 = {0u,0u,0u,0u};
    #pragma unroll
    for (int i = tid; i < NO_TOT/16; i += 256) rem4[i] = z4;
    __syncthreads();

    float lsum = 0.f;

    // ===== Phase 1: mark bitmap; coord loss once per batch (k==0) =====
    if (p1 && dp.valid) {
        removed[dp.now*SS + dp.cell] = 1;
        if (k == 0) {
            const float rax = 1.f/(1.f+expf(-e1));
            const float ray = 1.f/(1.f+expf(-e2));
            const float rw  = AW[dp.idx]*expf(e3);
            const float rh  = AH[dp.idx]*expf(e4);

            // iou_t with the reference's quirky formula (y1+1 inside the max)
            const float X1 = rax*DIVc - rw*0.5f, Y1 = ray*DIVc - rh*0.5f;
            const float X2 = rax*DIVc + rw*0.5f, Y2 = ray*DIVc + rh*0.5f;
            const float x1 = dp.ax*DIVc - dp.w*0.5f, y1 = dp.ay*DIVc - dp.h*0.5f;
            const float x2 = dp.ax*DIVc + dp.w*0.5f, y2 = dp.ay*DIVc + dp.h*0.5f;
            const float Bv  = (dp.w+1.f)*(dp.h+1.f);
            const float A2  = (rw+1.f)*(rh+1.f);
            const float CM2 = (fminf(X2,x2)-fmaxf(X1,x1)+1.f) *
                              (fminf(Y2,y2)-fmaxf(Y1,y1+1.f));
            const float iou_t = CM2/(A2+Bv-CM2);

            const float q0 = e0-iou_t, q1 = rax-dp.ax, q2 = ray-dp.ay,
                        q3 = rw-dp.w,  q4 = rh-dp.h;
            lsum += 5.f*q0*q0 + q1*q1 + q2*q2 + q3*q3 + q4*q4;
        }
    }

    // ===== Phase 2: BCE from prefetched v0/v1 (independent of bitmap) =====
    if (d0.valid) {
        const float label = 1.f/(1.f+expf(-v0));
        const float term = (cls0 == c0) ? fmaxf(logf(label),    -100.f)
                                        : fmaxf(log1pf(-label), -100.f);
        lsum -= term * (1.f/(float)Cc);
    }
    if (has1 && d1.valid) {
        const float label = 1.f/(1.f+expf(-v1));
        const float term = (cls1 == c1) ? fmaxf(logf(label),    -100.f)
                                        : fmaxf(log1pf(-label), -100.f);
        lsum -= term * (1.f/(float)Cc);
    }

    __syncthreads();   // bitmap complete

    // ===== Phase 3: noobj num (prefetched) + full-bitmap count =====
    float num = 0.f;
    #pragma unroll
    for (int i = 0; i < 4; ++i)
        if (pm[i] && !removed[tix[i]]) num += pre[i]*pre[i];

    int cnt = 0;
    #pragma unroll
    for (int i = tid; i < NO_TOT/16; i += 256) {
        const uint4 wd = rem4[i];
        const unsigned s = ((wd.x * 0x01010101u) >> 24)
                         + ((wd.y * 0x01010101u) >> 24)
                         + ((wd.z * 0x01010101u) >> 24)
                         + ((wd.w * 0x01010101u) >> 24);
        cnt += (int)s;
    }

    // ===== block reduce via shuffles =====
    #pragma unroll
    for (int o = 32; o > 0; o >>= 1) {
        lsum += __shfl_down(lsum, o);
        num  += __shfl_down(num,  o);
        cnt  += __shfl_down(cnt,  o);
    }
    const int wv = tid >> 6;
    if ((tid & 63) == 0) { wsf[wv] = lsum; wsn[wv] = num; wsc[wv] = cnt; }
    __syncthreads();

    // ===== FENCE-FREE single-dispatch tail =====
    // No __threadfence (no buffer_wbl2 / L2 writeback). Visibility via point
    // ops at the device coherence point:
    //   exchange(AGENT)  -> partial written through (one line)
    //   s_waitcnt vmcnt(0)-> own publish globally visible before the inc
    //   atomicInc        -> RMW at coherence point; wrap protocol (r4): for
    //                       any start >=511 (0xAA poison / steady-state 511)
    //                       old==510 is exactly the 512th arrival.
    if (tid == 0) {
        const float F  = wsf[0]+wsf[1]+wsf[2]+wsf[3];
        const float Nn = wsn[0]+wsn[1]+wsn[2]+wsn[3];
        const int   Ct = wsc[0]+wsc[1]+wsc[2]+wsc[3];
        const float pval = F + 0.5f * Nn / (float)(NO_TOT - Ct);
        __hip_atomic_exchange(&partial[blk], pval, __ATOMIC_RELAXED,
                              __HIP_MEMORY_SCOPE_AGENT);
        asm volatile("s_waitcnt vmcnt(0)" ::: "memory");
        const unsigned old = atomicInc(ctr, NBLK-1u);
        fin = (old == (unsigned)(NBLK-2));
    }
    __syncthreads();

    // ===== finisher: deterministic fixed-order reduce of 512 partials =====
    if (fin) {
        float v = __hip_atomic_load(&partial[tid],       __ATOMIC_RELAXED,
                                    __HIP_MEMORY_SCOPE_AGENT)
                + __hip_atomic_load(&partial[tid + 256], __ATOMIC_RELAXED,
                                    __HIP_MEMORY_SCOPE_AGENT);
        #pragma unroll
        for (int o = 32; o > 0; o >>= 1) v += __shfl_down(v, o);
        if ((tid & 63) == 0) wsf[tid >> 6] = v;
        __syncthreads();
        if (tid == 0) out[0] = wsf[0] + wsf[1] + wsf[2] + wsf[3];
    }
}

extern "C" void kernel_launch(void* const* d_in, const int* in_sizes, int n_in,
                              void* d_out, int out_size, void* d_ws, size_t ws_size,
                              hipStream_t stream) {
    const float*  x    = (const float*)d_in[0];
    const float4* geo4 = (const float4*)d_in[1];
    const int*    cls  = (const int*)d_in[2];
    float* out     = (float*)d_out;
    float* partial = (float*)d_ws;                        // 512 floats
    unsigned int* ctr = (unsigned int*)(partial + NBLK);  // 1 uint

    yolo_fused<<<NBLK, 256, 0, stream>>>(x, geo4, cls, out, partial, ctr);
}

// Round 9
// 14.862 us; speedup vs baseline: 1.7476x; 1.0891x over previous
//
#include <hip/hip_runtime.h>
#include <math.h>

#define Sd 52
#define SS (Sd*Sd)      // 2704
#define Cc 80
#define NCc 85
#define NCH 255
#define Bb 64
#define Mm 50
#define DIVc 8.0f
#define KB 8                    // blocks per batch
#define NBLK (Bb*KB)            // 512
#define BCE_SH  ((Mm*Cc)/KB)    // 500
#define NO_TOT  (3*SS)          // 8112
#define NO_SH   (NO_TOT/KB)     // 1014

__device__ __constant__ float AW[9] = {10.f,16.f,33.f,30.f,62.f,59.f,116.f,156.f,373.f};
__device__ __constant__ float AH[9] = {13.f,30.f,23.f,61.f,45.f,119.f,90.f,198.f,326.f};

struct Dec {
    int   idx, valid, now, cell, off;
    float ax, ay, w, h;
};

// Reference's quirky anchor IoU + cell decode; pure function of geo[b,m].
// Argmax via cross-multiplication (CM,D all > 0 for this data): no divides.
__device__ __forceinline__ Dec decode(const float4* __restrict__ geo4, int b, int m) {
    Dec d;
    const float4 g = geo4[b*Mm + m];
    const float cx = g.x, cy = g.y, w = g.z, h = g.w;
    // A=(aw+1)(ah+1), Bv=(w+1)(h+1), CM=(min(aw,w)+1)*(min(ah,h)-1), D=A+Bv-CM
    const float Bv = (w+1.f)*(h+1.f);
    float bCM = (fminf(AW[0],w)+1.f)*(fminf(AH[0],h)-1.f);
    float bD  = (AW[0]+1.f)*(AH[0]+1.f) + Bv - bCM;
    int idx = 0;
    #pragma unroll
    for (int i = 1; i < 9; ++i) {
        const float CM = (fminf(AW[i],w)+1.f)*(fminf(AH[i],h)-1.f);
        const float D  = (AW[i]+1.f)*(AH[i]+1.f) + Bv - CM;
        if (CM*bD > bCM*D) { bCM = CM; bD = D; idx = i; }  // first-max tie-break
    }
    d.idx   = idx;
    d.valid = (idx <= 2) ? 1 : 0;
    d.now   = idx < 2 ? idx : 2;
    int ix = (int)(cx * 0.125f); ix = ix < 0 ? 0 : (ix > Sd-1 ? Sd-1 : ix);
    int iy = (int)(cy * 0.125f); iy = iy < 0 ? 0 : (iy > Sd-1 ? Sd-1 : iy);
    d.cell = ix*Sd + iy;
    d.off  = (b*NCH + d.now*NCc)*SS + d.cell;
    d.ax = (cx - (float)ix*DIVc) * 0.125f;
    d.ay = (cy - (float)iy*DIVc) * 0.125f;
    d.w = w; d.h = h;
    return d;
}

__global__ __launch_bounds__(256, 2) void yolo_main(
    const float*  __restrict__ x,      // (B, 255, 52, 52)
    const float4* __restrict__ geo4,   // (B, 50) float4
    const int*    __restrict__ cls,    // (B, 50)
    float* __restrict__ partial)       // (NBLK,) in d_ws — fully overwritten
{
    const int blk = blockIdx.x;
    const int b   = blk >> 3;
    const int k   = blk & (KB-1);
    const int tid = threadIdx.x;

    __shared__ uint4 rem4[NO_TOT/16];            // 8112 B bitmap (now, s1, s2)
    unsigned char* removed = (unsigned char*)rem4;
    __shared__ float wsf[4], wsn[4];
    __shared__ int   wsc[4];

    // ===== issue ALL scattered global loads up front (latency overlap) =====
    // BCE pair 0: every thread re-decodes its own box (no barrier dependency).
    const int t0 = k*BCE_SH + tid;
    const int m0 = t0 / Cc, c0 = t0 - m0*Cc;
    const Dec d0 = decode(geo4, b, m0);
    const int cls0 = cls[b*Mm + m0];
    const float v0 = x[d0.off + (5+c0)*SS];          // in-bounds even if !valid

    // BCE pair 1 (tid < 244); clamp index for inactive lanes, mask at use.
    const bool has1 = tid < (BCE_SH - 256);
    const int t1 = t0 + 256;
    const int m1 = has1 ? t1 / Cc : m0;
    const int c1 = has1 ? (t1 - m1*Cc) : c0;
    const Dec d1 = decode(geo4, b, m1);
    const int cls1 = cls[b*Mm + m1];
    const float v1 = x[d1.off + (5+c1)*SS];

    // noobj preloads (coalesced, 4 per thread; only i=3 can be out-of-share)
    const float* xb = x + (size_t)b*NCH*SS;
    float pre[4]; int tix[4]; bool pm[4];
    #pragma unroll
    for (int i = 0; i < 4; ++i) {
        const int t = k*NO_SH + tid + i*256;
        pm[i]  = (t < (k+1)*NO_SH);
        tix[i] = pm[i] ? t : k*NO_SH;
        const int nw = tix[i] / SS, s = tix[i] - nw*SS;
        pre[i] = xb[nw*NCc*SS + s];
    }

    // phase-1 decode (tid<50) + coord-channel loads (k==0 blocks only)
    Dec dp; dp.valid = 0; dp.now = 0; dp.cell = 0; dp.idx = 0;
    float e0=0.f, e1=0.f, e2=0.f, e3=0.f, e4=0.f;
    const bool p1 = (tid < Mm);
    if (p1) {
        dp = decode(geo4, b, tid);
        if (k == 0) {
            e0 = x[dp.off];
            e1 = x[dp.off + 1*SS];
            e2 = x[dp.off + 2*SS];
            e3 = x[dp.off + 3*SS];
            e4 = x[dp.off + 4*SS];
        }
    }

    // ===== zero bitmap while loads are in flight (uint4: 2 iters) =====
    const uint4 z4 = {0u,0u,0u,0u};
    #pragma unroll
    for (int i = tid; i < NO_TOT/16; i += 256) rem4[i] = z4;
    __syncthreads();

    float lsum = 0.f;

    // ===== Phase 1: mark bitmap; coord loss once per batch (k==0) =====
    if (p1 && dp.valid) {
        removed[dp.now*SS + dp.cell] = 1;
        if (k == 0) {
            const float rax = 1.f/(1.f+expf(-e1));
            const float ray = 1.f/(1.f+expf(-e2));
            const float rw  = AW[dp.idx]*expf(e3);
            const float rh  = AH[dp.idx]*expf(e4);

            // iou_t with the reference's quirky formula (y1+1 inside the max)
            const float X1 = rax*DIVc - rw*0.5f, Y1 = ray*DIVc - rh*0.5f;
            const float X2 = rax*DIVc + rw*0.5f, Y2 = ray*DIVc + rh*0.5f;
            const float x1 = dp.ax*DIVc - dp.w*0.5f, y1 = dp.ay*DIVc - dp.h*0.5f;
            const float x2 = dp.ax*DIVc + dp.w*0.5f, y2 = dp.ay*DIVc + dp.h*0.5f;
            const float Bv  = (dp.w+1.f)*(dp.h+1.f);
            const float A2  = (rw+1.f)*(rh+1.f);
            const float CM2 = (fminf(X2,x2)-fmaxf(X1,x1)+1.f) *
                              (fminf(Y2,y2)-fmaxf(Y1,y1+1.f));
            const float iou_t = CM2/(A2+Bv-CM2);

            const float q0 = e0-iou_t, q1 = rax-dp.ax, q2 = ray-dp.ay,
                        q3 = rw-dp.w,  q4 = rh-dp.h;
            lsum += 5.f*q0*q0 + q1*q1 + q2*q2 + q3*q3 + q4*q4;
        }
    }

    // ===== Phase 2: BCE from prefetched v0/v1 (independent of bitmap) =====
    if (d0.valid) {
        const float label = 1.f/(1.f+expf(-v0));
        const float term = (cls0 == c0) ? fmaxf(logf(label),    -100.f)
                                        : fmaxf(log1pf(-label), -100.f);
        lsum -= term * (1.f/(float)Cc);
    }
    if (has1 && d1.valid) {
        const float label = 1.f/(1.f+expf(-v1));
        const float term = (cls1 == c1) ? fmaxf(logf(label),    -100.f)
                                        : fmaxf(log1pf(-label), -100.f);
        lsum -= term * (1.f/(float)Cc);
    }

    __syncthreads();   // bitmap complete

    // ===== Phase 3: noobj num (prefetched) + full-bitmap count =====
    float num = 0.f;
    #pragma unroll
    for (int i = 0; i < 4; ++i)
        if (pm[i] && !removed[tix[i]]) num += pre[i]*pre[i];

    int cnt = 0;
    #pragma unroll
    for (int i = tid; i < NO_TOT/16; i += 256) {
        const uint4 wd = rem4[i];
        const unsigned s = ((wd.x * 0x01010101u) >> 24)
                         + ((wd.y * 0x01010101u) >> 24)
                         + ((wd.z * 0x01010101u) >> 24)
                         + ((wd.w * 0x01010101u) >> 24);
        cnt += (int)s;
    }

    // ===== block reduce via shuffles; plain store (no atomics) =====
    #pragma unroll
    for (int o = 32; o > 0; o >>= 1) {
        lsum += __shfl_down(lsum, o);
        num  += __shfl_down(num,  o);
        cnt  += __shfl_down(cnt,  o);
    }
    const int wv = tid >> 6;
    if ((tid & 63) == 0) { wsf[wv] = lsum; wsn[wv] = num; wsc[wv] = cnt; }
    __syncthreads();
    if (tid == 0) {
        const float F  = wsf[0]+wsf[1]+wsf[2]+wsf[3];
        const float Nn = wsn[0]+wsn[1]+wsn[2]+wsn[3];
        const int   Ct = wsc[0]+wsc[1]+wsc[2]+wsc[3];
        partial[blk] = F + 0.5f * Nn / (float)(NO_TOT - Ct);
    }
}

// 1 wave (64 lanes): deterministic fixed-order 512 -> 1 reduce. No LDS.
__global__ __launch_bounds__(64) void yolo_finish(
    const float* __restrict__ partial, float* __restrict__ out)
{
    const int tid = threadIdx.x;
    float v = 0.f;
    #pragma unroll
    for (int i = 0; i < NBLK/64; ++i) v += partial[tid + i*64];
    #pragma unroll
    for (int o = 32; o > 0; o >>= 1) v += __shfl_down(v, o);
    if (tid == 0) out[0] = v;
}

extern "C" void kernel_launch(void* const* d_in, const int* in_sizes, int n_in,
                              void* d_out, int out_size, void* d_ws, size_t ws_size,
                              hipStream_t stream) {
    const float*  x    = (const float*)d_in[0];
    const float4* geo4 = (const float4*)d_in[1];
    const int*    cls  = (const int*)d_in[2];
    float* out     = (float*)d_out;
    float* partial = (float*)d_ws;     // NBLK floats, fully overwritten each call

    yolo_main<<<NBLK, 256, 0, stream>>>(x, geo4, cls, partial);
    yolo_finish<<<1, 64, 0, stream>>>(partial, out);
}